// Round 1
// baseline (203.617 us; speedup 1.0000x reference)
//
#include <hip/hip_runtime.h>
#include <hip/hip_bf16.h>

#define N1 8192
#define N2 16384
#define DIM 256
#define NSPLIT 4
#define BM 64
#define BN 64
#define COLS_PER_SPLIT (N2 / NSPLIT)   // 4096
#define NPART (NSPLIT * 4)             // partial top3 sets per row (4 splits x 4 waves)

typedef short v8s  __attribute__((ext_vector_type(8)));   // 8 x bf16 bits (4 VGPR)
typedef float f32x4 __attribute__((ext_vector_type(4)));

__device__ __forceinline__ void top3_insert(float v, float& t0, float& t1, float& t2) {
    // branchless sorted-insert into t0 >= t1 >= t2
    float m0 = fminf(t0, v);
    float m1 = fminf(t1, m0);
    t0 = fmaxf(t0, v);
    t1 = fmaxf(t1, m0);
    t2 = fmaxf(t2, m1);
}

// One wave per row: fp32 sum-of-squares, rsqrt in fp32, emit bf16 normalized row.
__global__ __launch_bounds__(256) void normalize_kernel(
        const float* __restrict__ in, __hip_bfloat16* __restrict__ out, int nrows) {
    const int row  = blockIdx.x * 4 + (threadIdx.x >> 6);
    const int lane = threadIdx.x & 63;
    if (row >= nrows) return;
    const float4 v = *(const float4*)(in + (size_t)row * DIM + lane * 4);
    float s = v.x * v.x + v.y * v.y + v.z * v.z + v.w * v.w;
    #pragma unroll
    for (int off = 32; off; off >>= 1) s += __shfl_xor(s, off, 64);
    const float inv = 1.0f / sqrtf(s);
    __hip_bfloat16 o[4];
    o[0] = __float2bfloat16(v.x * inv);
    o[1] = __float2bfloat16(v.y * inv);
    o[2] = __float2bfloat16(v.z * inv);
    o[3] = __float2bfloat16(v.w * inv);
    *(uint2*)(out + (size_t)row * DIM + lane * 4) = *(uint2*)o;
}

// Block: 4 waves, 64 rows of A held in registers (all waves same rows).
// Wave w covers cols {col0 + 64*it + (lane&15)} -> running top3 per (lane,row).
__global__ __launch_bounds__(256, 2) void gemm_top3_kernel(
        const __hip_bfloat16* __restrict__ A, const __hip_bfloat16* __restrict__ B,
        float* __restrict__ partial) {
    const int tid   = threadIdx.x;
    const int wave  = tid >> 6;
    const int lane  = tid & 63;
    const int lo    = lane & 15;
    const int quad  = lane >> 4;
    const int rb    = blockIdx.x % (N1 / BM);
    const int split = blockIdx.x / (N1 / BM);
    const int row0  = rb * BM;
    const int col0  = split * COLS_PER_SPLIT + wave * 16;

    // A fragments: afrag[rt][ks] -> rows row0+rt*16+lo, k = ks*32 + quad*8 + j
    v8s afrag[4][8];
    #pragma unroll
    for (int rt = 0; rt < 4; rt++) {
        const __hip_bfloat16* ap = A + (size_t)(row0 + rt * 16 + lo) * DIM + quad * 8;
        #pragma unroll
        for (int ks = 0; ks < 8; ks++)
            afrag[rt][ks] = *(const v8s*)(ap + ks * 32);
    }

    float t0[16], t1[16], t2[16];
    #pragma unroll
    for (int i = 0; i < 16; i++) { t0[i] = -1e30f; t1[i] = -1e30f; t2[i] = -1e30f; }

    const __hip_bfloat16* bbase = B + (size_t)(col0 + lo) * DIM + quad * 8;

    for (int it = 0; it < COLS_PER_SPLIT / BN; ++it) {
        const __hip_bfloat16* bp = bbase + (size_t)it * BN * DIM;
        f32x4 acc[4];
        #pragma unroll
        for (int rt = 0; rt < 4; rt++) acc[rt] = (f32x4){0.f, 0.f, 0.f, 0.f};
        #pragma unroll
        for (int ks = 0; ks < 8; ks++) {
            v8s b = *(const v8s*)(bp + ks * 32);
            #pragma unroll
            for (int rt = 0; rt < 4; rt++)
                acc[rt] = __builtin_amdgcn_mfma_f32_16x16x32_bf16(afrag[rt][ks], b, acc[rt], 0, 0, 0);
        }
        #pragma unroll
        for (int rt = 0; rt < 4; rt++) {
            #pragma unroll
            for (int r = 0; r < 4; r++) {
                const int i = rt * 4 + r;
                top3_insert(acc[rt][r], t0[i], t1[i], t2[i]);
            }
        }
    }

    // merge across the 16 lanes (same rows, different col residues)
    #pragma unroll
    for (int step = 1; step < 16; step <<= 1) {
        #pragma unroll
        for (int i = 0; i < 16; i++) {
            float b0 = __shfl_xor(t0[i], step, 64);
            float b1 = __shfl_xor(t1[i], step, 64);
            float b2 = __shfl_xor(t2[i], step, 64);
            top3_insert(b0, t0[i], t1[i], t2[i]);
            top3_insert(b1, t0[i], t1[i], t2[i]);
            top3_insert(b2, t0[i], t1[i], t2[i]);
        }
    }

    if (lo == 0) {
        #pragma unroll
        for (int rt = 0; rt < 4; rt++) {
            #pragma unroll
            for (int r = 0; r < 4; r++) {
                const int i = rt * 4 + r;
                const int row = row0 + rt * 16 + quad * 4 + r;
                float* p = partial + ((size_t)row * NPART + (split * 4 + wave)) * 3;
                p[0] = t0[i]; p[1] = t1[i]; p[2] = t2[i];
            }
        }
    }
}

__global__ __launch_bounds__(256) void merge_kernel(
        const float* __restrict__ partial, float* __restrict__ out) {
    const int row = blockIdx.x * 256 + threadIdx.x;
    if (row >= N1) return;
    const float* p = partial + (size_t)row * NPART * 3;
    float t0 = -1e30f, t1 = -1e30f, t2 = -1e30f;
    #pragma unroll
    for (int i = 0; i < NPART * 3; i++) top3_insert(p[i], t0, t1, t2);
    out[row] = (t0 + t1 + t2) * (1.0f / 3.0f);
}

extern "C" void kernel_launch(void* const* d_in, const int* in_sizes, int n_in,
                              void* d_out, int out_size, void* d_ws, size_t ws_size,
                              hipStream_t stream) {
    const float* tA = (const float*)d_in[0];
    const float* tB = (const float*)d_in[1];
    float* out = (float*)d_out;

    __hip_bfloat16* An = (__hip_bfloat16*)d_ws;
    __hip_bfloat16* Bn = An + (size_t)N1 * DIM;
    float* partial = (float*)(Bn + (size_t)N2 * DIM);

    normalize_kernel<<<N1 / 4, 256, 0, stream>>>(tA, An, N1);
    normalize_kernel<<<N2 / 4, 256, 0, stream>>>(tB, Bn, N2);
    gemm_top3_kernel<<<(N1 / BM) * NSPLIT, 256, 0, stream>>>(An, Bn, partial);
    merge_kernel<<<N1 / 256, 256, 0, stream>>>(partial, out);
}

// Round 2
// 201.147 us; speedup vs baseline: 1.0123x; 1.0123x over previous
//
#include <hip/hip_runtime.h>
#include <hip/hip_bf16.h>

#define N1 8192
#define N2 16384
#define DIM 256
#define NSPLIT 4
#define BM 64
#define BN 64
#define COLS_PER_SPLIT (N2 / NSPLIT)   // 4096
#define NPART (NSPLIT * 4)             // partial top3 sets per row

typedef short v8s  __attribute__((ext_vector_type(8)));   // 8 x bf16 bits (4 VGPR)
typedef float f32x4 __attribute__((ext_vector_type(4)));

__device__ __forceinline__ void top3_insert(float v, float& t0, float& t1, float& t2) {
    // invariant t0 >= t1 >= t2; 4 VALU ops (max, med3, min, max)
    float nt1 = __builtin_amdgcn_fmed3f(t0, t1, v);
    float nt2 = fmaxf(t2, fminf(t1, v));
    t0 = fmaxf(t0, v);
    t1 = nt1;
    t2 = nt2;
}

// One wave per row over A then B: fp32 sumsq, rsqrt, emit bf16 normalized row.
__global__ __launch_bounds__(256) void normalize_kernel(
        const float* __restrict__ inA, const float* __restrict__ inB,
        __hip_bfloat16* __restrict__ outA, __hip_bfloat16* __restrict__ outB) {
    const int gw   = blockIdx.x * 4 + (threadIdx.x >> 6);   // global wave id = row id
    const int lane = threadIdx.x & 63;
    const float* in;
    __hip_bfloat16* out;
    int row;
    if (gw < N1) { in = inA; out = outA; row = gw; }
    else         { in = inB; out = outB; row = gw - N1; }
    const float4 v = *(const float4*)(in + (size_t)row * DIM + lane * 4);
    float s = v.x * v.x + v.y * v.y + v.z * v.z + v.w * v.w;
    #pragma unroll
    for (int off = 32; off; off >>= 1) s += __shfl_xor(s, off, 64);
    const float inv = 1.0f / sqrtf(s);
    __hip_bfloat16 o[4];
    o[0] = __float2bfloat16(v.x * inv);
    o[1] = __float2bfloat16(v.y * inv);
    o[2] = __float2bfloat16(v.z * inv);
    o[3] = __float2bfloat16(v.w * inv);
    *(uint2*)(out + (size_t)row * DIM + lane * 4) = *(uint2*)o;
}

// Block: 4 waves. 64 rows of A pinned in registers (128 VGPR/lane).
// Wave w covers cols {col0 + 64*it + (lane&15)}; streaming top3 per (lane,row).
__global__ __launch_bounds__(256, 2) void gemm_top3_kernel(
        const __hip_bfloat16* __restrict__ A, const __hip_bfloat16* __restrict__ B,
        float* __restrict__ partial) {
    const int tid   = threadIdx.x;
    const int wave  = tid >> 6;
    const int lane  = tid & 63;
    const int lo    = lane & 15;
    const int quad  = lane >> 4;
    const int rb    = blockIdx.x % (N1 / BM);
    const int split = blockIdx.x / (N1 / BM);
    const int row0  = rb * BM;
    const int col0  = split * COLS_PER_SPLIT + wave * 16;

    // A fragments: afrag[rt][ks] -> rows row0+rt*16+lo, k = ks*32 + quad*8 + j
    v8s afrag[4][8];
    #pragma unroll
    for (int rt = 0; rt < 4; rt++) {
        const __hip_bfloat16* ap = A + (size_t)(row0 + rt * 16 + lo) * DIM + quad * 8;
        #pragma unroll
        for (int ks = 0; ks < 8; ks++)
            afrag[rt][ks] = *(const v8s*)(ap + ks * 32);
    }
    // Pin A in registers: forbid the compiler from sinking these loads into the loop.
    #pragma unroll
    for (int rt = 0; rt < 4; rt++)
        #pragma unroll
        for (int ks = 0; ks < 8; ks++)
            asm volatile("" : "+v"(afrag[rt][ks]));

    float t0[16], t1[16], t2[16];
    #pragma unroll
    for (int i = 0; i < 16; i++) { t0[i] = -1e30f; t1[i] = -1e30f; t2[i] = -1e30f; }

    const __hip_bfloat16* bp = B + (size_t)(col0 + lo) * DIM + quad * 8;

    for (int it = 0; it < COLS_PER_SPLIT / BN; ++it) {
        // Load all 8 B fragments up front (constant byte offsets 0..448).
        v8s b[8];
        #pragma unroll
        for (int ks = 0; ks < 8; ks++) b[ks] = *(const v8s*)(bp + ks * 32);
        bp += (size_t)BN * DIM;

        f32x4 acc[4];
        #pragma unroll
        for (int rt = 0; rt < 4; rt++) acc[rt] = (f32x4){0.f, 0.f, 0.f, 0.f};
        #pragma unroll
        for (int ks = 0; ks < 8; ks++) {
            #pragma unroll
            for (int rt = 0; rt < 4; rt++)
                acc[rt] = __builtin_amdgcn_mfma_f32_16x16x32_bf16(afrag[rt][ks], b[ks], acc[rt], 0, 0, 0);
        }
        #pragma unroll
        for (int rt = 0; rt < 4; rt++) {
            #pragma unroll
            for (int r = 0; r < 4; r++) {
                const int i = rt * 4 + r;
                top3_insert(acc[rt][r], t0[i], t1[i], t2[i]);
            }
        }
    }

    // merge across the 16 lanes (same rows, different col residues)
    #pragma unroll
    for (int step = 1; step < 16; step <<= 1) {
        #pragma unroll
        for (int i = 0; i < 16; i++) {
            float b0 = __shfl_xor(t0[i], step, 64);
            float b1 = __shfl_xor(t1[i], step, 64);
            float b2 = __shfl_xor(t2[i], step, 64);
            top3_insert(b0, t0[i], t1[i], t2[i]);
            top3_insert(b1, t0[i], t1[i], t2[i]);
            top3_insert(b2, t0[i], t1[i], t2[i]);
        }
    }

    if (lo == 0) {
        #pragma unroll
        for (int rt = 0; rt < 4; rt++) {
            #pragma unroll
            for (int r = 0; r < 4; r++) {
                const int i = rt * 4 + r;
                const int row = row0 + rt * 16 + quad * 4 + r;
                float* p = partial + ((size_t)row * NPART + (split * 4 + wave)) * 3;
                p[0] = t0[i]; p[1] = t1[i]; p[2] = t2[i];
            }
        }
    }
}

__global__ __launch_bounds__(256) void merge_kernel(
        const float* __restrict__ partial, float* __restrict__ out) {
    const int row = blockIdx.x * 256 + threadIdx.x;
    if (row >= N1) return;
    const float* p = partial + (size_t)row * NPART * 3;
    float t0 = -1e30f, t1 = -1e30f, t2 = -1e30f;
    #pragma unroll
    for (int i = 0; i < NPART * 3; i++) top3_insert(p[i], t0, t1, t2);
    out[row] = (t0 + t1 + t2) * (1.0f / 3.0f);
}

extern "C" void kernel_launch(void* const* d_in, const int* in_sizes, int n_in,
                              void* d_out, int out_size, void* d_ws, size_t ws_size,
                              hipStream_t stream) {
    const float* tA = (const float*)d_in[0];
    const float* tB = (const float*)d_in[1];
    float* out = (float*)d_out;

    __hip_bfloat16* An = (__hip_bfloat16*)d_ws;
    __hip_bfloat16* Bn = An + (size_t)N1 * DIM;
    float* partial = (float*)(Bn + (size_t)N2 * DIM);

    normalize_kernel<<<(N1 + N2) / 4, 256, 0, stream>>>(tA, tB, An, Bn);
    gemm_top3_kernel<<<(N1 / BM) * NSPLIT, 256, 0, stream>>>(An, Bn, partial);
    merge_kernel<<<N1 / 256, 256, 0, stream>>>(partial, out);
}